// Round 6
// baseline (245.428 us; speedup 1.0000x reference)
//
#include <hip/hip_runtime.h>

// NMS3D: x (4,2,64,256,256) f32, 3x3x3 neighborhood-max excluding center,
// edge padding == index clamping (exact match, incl. zeroed boundary shell).
//
// R6: H-MARCH. Each wave owns (n, z, 16-row h-segment) and walks h
// sequentially, loading one row from each of slices z-1,z,z+1 per step.
// All four memory streams per wave (3 read, 1 write) are CONTIGUOUS in h
// (1 KB/step, no 256KB z-hops) - attacks the stream-shape bottleneck that
// left R1-R5 flat at 76-86us regardless of load count / LDS / prefetch.
// Rolling 3-deep hmax3 history per slice in registers; math identical.

constexpr int D_   = 64;
constexpr int H_   = 256;
constexpr int W_   = 256;
constexpr int HW_  = H_ * W_;
constexpr int NVOL = 8;     // B * CH
constexpr int HSEG = 16;    // output rows per wave

__device__ __forceinline__ float f3(float a, float b, float c) {
    return fmaxf(fmaxf(a, b), c);
}

// hm = horizontal 3-max of row; nb = horizontal max EXCLUDING center
__device__ __forceinline__ void rowfold(const float4 r, int tx,
                                        float4& hm, float4& nb)
{
    float rL = __shfl_up(r.w, 1);   if (tx == 0)  rL = r.x;
    float rR = __shfl_down(r.x, 1); if (tx == 63) rR = r.w;
    hm.x = f3(rL, r.x, r.y);  hm.y = f3(r.x, r.y, r.z);
    hm.z = f3(r.y, r.z, r.w); hm.w = f3(r.z, r.w, rR);
    nb.x = fmaxf(rL, r.y);    nb.y = fmaxf(r.x, r.z);
    nb.z = fmaxf(r.y, r.w);   nb.w = fmaxf(r.z, rR);
}

__global__ __launch_bounds__(256, 4)
void nms3d(const float* __restrict__ x, float* __restrict__ out)
{
    const int tx = threadIdx.x;            // 0..63 -> W via float4
    const int ty = threadIdx.y;            // 0..3  -> z within chunk
    const int z  = (blockIdx.x << 2) + ty; // 0..63
    const int h0 = blockIdx.y * HSEG;
    const int n  = blockIdx.z;
    const int c  = tx << 2;

    const float* __restrict__ base = x + (size_t)n * D_ * HW_;
    const float* __restrict__ pm = base + (size_t)max(z - 1, 0)      * HW_;
    const float* __restrict__ pc = base + (size_t)z                  * HW_;
    const float* __restrict__ pp = base + (size_t)min(z + 1, D_ - 1) * HW_;
    float* __restrict__ ob = out + (size_t)n * D_ * HW_ + (size_t)z * HW_;

    // preload rows at clamp(h0-1)
    const int r0 = max(h0 - 1, 0) * W_ + c;
    float4 rm = *(const float4*)(pm + r0);
    float4 rc = *(const float4*)(pc + r0);
    float4 rp = *(const float4*)(pp + r0);

    // rolling hmax3 history per slice (m: z-1, c: z, p: z+1), nb/raw of row h-1
    float4 m0 = {0,0,0,0}, m1 = {0,0,0,0};
    float4 c0 = {0,0,0,0}, c1 = {0,0,0,0};
    float4 p0 = {0,0,0,0}, p1 = {0,0,0,0};
    float4 nb1 = {0,0,0,0}, b1 = {0,0,0,0};

#pragma unroll
    for (int t = 0; t < HSEG + 2; ++t) {
        // prefetch next row triple (contiguous in h per stream)
        float4 rmn, rcn, rpn;
        if (t <= HSEG) {
            const int rn = min(h0 + t, H_ - 1) * W_ + c;
            rmn = *(const float4*)(pm + rn);
            rcn = *(const float4*)(pc + rn);
            rpn = *(const float4*)(pp + rn);
        }

        // fold current rows (row hl = h0-1+t, clamped)
        float4 m2, p2, c2, nb2, dum;
        rowfold(rm, tx, m2, dum);
        rowfold(rp, tx, p2, dum);
        rowfold(rc, tx, c2, nb2);

        if (t >= 2) {
            // output row r = h0+t-2:
            // max_nc = max( vmax9(z-1,r), vmax9(z+1,r), cross8(z,r) )
            float4 mx, o;
            mx.x = f3(f3(m0.x, m1.x, m2.x), f3(p0.x, p1.x, p2.x), f3(c0.x, c2.x, nb1.x));
            mx.y = f3(f3(m0.y, m1.y, m2.y), f3(p0.y, p1.y, p2.y), f3(c0.y, c2.y, nb1.y));
            mx.z = f3(f3(m0.z, m1.z, m2.z), f3(p0.z, p1.z, p2.z), f3(c0.z, c2.z, nb1.z));
            mx.w = f3(f3(m0.w, m1.w, m2.w), f3(p0.w, p1.w, p2.w), f3(c0.w, c2.w, nb1.w));
            o.x = b1.x > mx.x ? b1.x : 0.0f;
            o.y = b1.y > mx.y ? b1.y : 0.0f;
            o.z = b1.z > mx.z ? b1.z : 0.0f;
            o.w = b1.w > mx.w ? b1.w : 0.0f;
            *(float4*)(ob + (size_t)(h0 + t - 2) * W_ + c) = o;
        }

        // shift history
        m0 = m1; m1 = m2;
        c0 = c1; c1 = c2;
        p0 = p1; p1 = p2;
        nb1 = nb2; b1 = rc;
        rm = rmn; rc = rcn; rp = rpn;
    }
}

extern "C" void kernel_launch(void* const* d_in, const int* in_sizes, int n_in,
                              void* d_out, int out_size, void* d_ws, size_t ws_size,
                              hipStream_t stream)
{
    const float* x = (const float*)d_in[0];
    float* out = (float*)d_out;
    dim3 block(64, 4, 1);                     // 4 waves: z-chunk of 4 planes
    dim3 grid(D_ / 4, H_ / HSEG, NVOL);       // 16 x 16 x 8 = 2048 blocks
    nms3d<<<grid, block, 0, stream>>>(x, out);
}

// Round 7
// 232.342 us; speedup vs baseline: 1.0563x; 1.0563x over previous
//
#include <hip/hip_runtime.h>

// NMS3D: x (4,2,64,256,256) f32, 3x3x3 neighborhood-max excluding center,
// edge padding == index clamping (exact match, incl. zeroed boundary shell).
//
// R7: async DMA pipeline. Evidence: VGPR_Count 28-40 across R1-R6 proves the
// register allocator collapsed every source-level prefetch (9 live float4
// bufs needed, never allocated) -> each body re-exposed full load latency.
// Fix: __builtin_amdgcn_global_load_lds into a WAVE-PRIVATE 3-slot LDS ring
// (3 rows x 1KB per slice). No __syncthreads anywhere -> no compiler
// vmcnt(0) drain; 2 slices (6 DMAs) always in flight; hand-placed partial
// s_waitcnt vmcnt(N) (in-order retirement, stores counted in N).
// Compute identical to R2: vertical fold, 4 shuffles, max tree.

constexpr int D_   = 64;
constexpr int H_   = 256;
constexpr int W_   = 256;
constexpr int HW_  = H_ * W_;
constexpr int NVOL = 8;    // B * CH
constexpr int DC   = 8;    // depth slices emitted per block

__device__ __forceinline__ float f3(float a, float b, float c) {
    return fmaxf(fmaxf(a, b), c);
}

// one row (1 KB) global->LDS DMA: lane i moves 16 B; lds base wave-uniform
__device__ __forceinline__ void dma_row(const float* g, float* l) {
    __builtin_amdgcn_global_load_lds(
        (const __attribute__((address_space(1))) void*)g,
        (__attribute__((address_space(3))) void*)l,
        16, 0, 0);
}

__global__ __launch_bounds__(256, 4)
void nms3d(const float* __restrict__ x, float* __restrict__ out)
{
    // [wave][ring slot][row a/b/d][W] = 36 KB
    __shared__ float buf[4][3][3][W_];

    const int tx = threadIdx.x;             // 0..63 -> W via float4
    const int ty = threadIdx.y;             // 0..3 = wave id (uniform in wave)
    const int h  = (blockIdx.y << 2) + ty;  // 0..255
    const int n  = blockIdx.z;              // 0..7
    const int z0 = blockIdx.x * DC;
    const int c  = tx << 2;

    const float* __restrict__ base  = x   + (size_t)n * D_ * HW_;
    float* __restrict__       obase = out + (size_t)n * D_ * HW_;

    const int r0 = (h == 0)      ? 0      : h - 1;
    const int r2 = (h == H_ - 1) ? H_ - 1 : h + 1;

    // stage slice for body s (z = z0-1+s, clamped) into ring slot s%3
    auto stage = [&](int s) {
        const int zc = min(max(z0 - 1 + s, 0), D_ - 1);
        const float* sp = base + (size_t)zc * HW_;
        float* slot = &buf[ty][s % 3][0][0];
        dma_row(sp + r0 * W_ + c, slot);            // row a
        dma_row(sp + h  * W_ + c, slot + W_);       // row b
        dma_row(sp + r2 * W_ + c, slot + 2 * W_);   // row d
    };

    // prologue: 2 slices in flight before first body
    stage(0);
    stage(1);

    // rolling depth state
    float4 vm9_pp = {0,0,0,0};  // vmax9[z-2]
    float4 vm9_p  = {0,0,0,0};  // vmax9[z-1]
    float4 cr8_p  = {0,0,0,0};  // cross8[z-1]
    float4 vprev  = {0,0,0,0};  // v[z-1]

#pragma unroll
    for (int t = 0; t < DC + 2; ++t) {      // bodies 0..9
        const int zi = z0 - 1 + t;

        if (t + 2 <= DC + 1) stage(t + 2);  // keep 2 slices in flight

        // wait until slice t's 3 DMAs retired. vm-op issue order:
        // pre:T0,T1 | B0:T2 | B1:T3 | B2:T4,S2 | B3:T5,S3 | ... | B8:S8 | B9:S9
        // ops younger than T(t): t<=2 -> 6; t==3 -> 7; 4<=t<=7 -> 8;
        // t==8 -> 5; t==9 -> 2. (stores count in vmcnt on gfx9)
        if      (t <= 2) asm volatile("s_waitcnt vmcnt(6)" ::: "memory");
        else if (t == 3) asm volatile("s_waitcnt vmcnt(7)" ::: "memory");
        else if (t <= 7) asm volatile("s_waitcnt vmcnt(8)" ::: "memory");
        else if (t == 8) asm volatile("s_waitcnt vmcnt(5)" ::: "memory");
        else             asm volatile("s_waitcnt vmcnt(2)" ::: "memory");

        const int sl = t % 3;
        const float4 a = *(const float4*)&buf[ty][sl][0][c];
        const float4 b = *(const float4*)&buf[ty][sl][1][c];
        const float4 d = *(const float4*)&buf[ty][sl][2][c];

        float4 va;
        va.x = fmaxf(a.x, d.x); va.y = fmaxf(a.y, d.y);
        va.z = fmaxf(a.z, d.z); va.w = fmaxf(a.w, d.w);

        float vaL = __shfl_up(va.w, 1);   if (tx == 0)  vaL = va.x;
        float vaR = __shfl_down(va.x, 1); if (tx == 63) vaR = va.w;
        float bL  = __shfl_up(b.w, 1);    if (tx == 0)  bL  = b.x;
        float bR  = __shfl_down(b.x, 1);  if (tx == 63) bR  = b.w;

        float4 hv;
        hv.x = f3(vaL, va.x, va.y);  hv.y = f3(va.x, va.y, va.z);
        hv.z = f3(va.y, va.z, va.w); hv.w = f3(va.z, va.w, vaR);
        float4 nb;
        nb.x = fmaxf(bL, b.y);   nb.y = fmaxf(b.x, b.z);
        nb.z = fmaxf(b.y, b.w);  nb.w = fmaxf(b.z, bR);

        float4 c8, cu;                       // cross8[zi], vmax9[zi]
        c8.x = fmaxf(hv.x, nb.x); c8.y = fmaxf(hv.y, nb.y);
        c8.z = fmaxf(hv.z, nb.z); c8.w = fmaxf(hv.w, nb.w);
        cu.x = fmaxf(c8.x, b.x);  cu.y = fmaxf(c8.y, b.y);
        cu.z = fmaxf(c8.z, b.z);  cu.w = fmaxf(c8.w, b.w);

        if (zi > z0) {
            // out[zi-1]: max_nc = max(vmax9[zi-2], cross8[zi-1], vmax9[zi])
            float4 mx, o;
            mx.x = f3(vm9_pp.x, cr8_p.x, cu.x);
            mx.y = f3(vm9_pp.y, cr8_p.y, cu.y);
            mx.z = f3(vm9_pp.z, cr8_p.z, cu.z);
            mx.w = f3(vm9_pp.w, cr8_p.w, cu.w);
            o.x = vprev.x > mx.x ? vprev.x : 0.0f;
            o.y = vprev.y > mx.y ? vprev.y : 0.0f;
            o.z = vprev.z > mx.z ? vprev.z : 0.0f;
            o.w = vprev.w > mx.w ? vprev.w : 0.0f;
            *(float4*)(obase + (size_t)(zi - 1) * HW_ + (size_t)h * W_ + c) = o;
        }
        vm9_pp = vm9_p; vm9_p = cu; cr8_p = c8; vprev = b;
    }
}

extern "C" void kernel_launch(void* const* d_in, const int* in_sizes, int n_in,
                              void* d_out, int out_size, void* d_ws, size_t ws_size,
                              hipStream_t stream)
{
    const float* x = (const float*)d_in[0];
    float* out = (float*)d_out;
    dim3 block(64, 4, 1);
    dim3 grid(D_ / DC, H_ / 4, NVOL);   // 8 x 64 x 8 = 4096 blocks
    nms3d<<<grid, block, 0, stream>>>(x, out);
}